// Round 2
// baseline (159.343 us; speedup 1.0000x reference)
//
#include <hip/hip_runtime.h>
#include <hip/hip_bf16.h>
#include <math.h>

// Problem constants
#define B_    2
#define K_    8
#define C_    64
#define CH_   32      // C/2
#define H_    128
#define W_    128
#define HW_   16384   // H*W
#define BN_EPS 1e-5f
#define SIGMA_MAX 0.3f
#define COV_SHRINK 0.1f
#define COV_DELTA 1e-3f

// ---------------------------------------------------------------------------
// Kernel 1: sensor maps, prep folded in. One thread per (b,k,h,w).
// o-loop outer so w1[o][0..63] is contiguous -> s_load_dwordx16 scalar loads.
// BN fold (rsqrt etc.) done inline per o (~7 VALU extra per o, +11% VALU,
// still below the 64 MiB HBM floor of ~10.7 us).
// ---------------------------------------------------------------------------
__global__ void __launch_bounds__(256)
stage1_kernel(const float* __restrict__ X,
              const float* __restrict__ w1,        // [32][64] contiguous rows
              const float* __restrict__ bn_scale,
              const float* __restrict__ bn_bias,
              const float* __restrict__ bn_mean,
              const float* __restrict__ bn_var,
              const float* __restrict__ w2,        // [32]
              float* __restrict__ S) {
    int idx = blockIdx.x * blockDim.x + threadIdx.x;   // 0 .. B*K*HW-1
    int hw = idx & (HW_ - 1);
    int bk = idx >> 14;
    const float* xp = X + (size_t)bk * (C_ * HW_) + hw;

    // One coalesced sweep: x[c] in VGPRs (64 regs), loads all in flight.
    float x[C_];
#pragma unroll
    for (int c = 0; c < C_; ++c) x[c] = xp[(size_t)c * HW_];

    float out = 0.f;
#pragma unroll
    for (int o = 0; o < CH_; ++o) {
        const float* wrow = w1 + o * C_;           // contiguous -> scalar loads
        float s0 = 0.f, s1 = 0.f, s2 = 0.f, s3 = 0.f;  // break fmac dep chain
#pragma unroll
        for (int c = 0; c < C_; c += 4) {
            s0 = fmaf(wrow[c],     x[c],     s0);
            s1 = fmaf(wrow[c + 1], x[c + 1], s1);
            s2 = fmaf(wrow[c + 2], x[c + 2], s2);
            s3 = fmaf(wrow[c + 3], x[c + 3], s3);
        }
        float s = (s0 + s1) + (s2 + s3);
        float inv = bn_scale[o] * rsqrtf(bn_var[o] + BN_EPS);
        float h = fmaf(s, inv, fmaf(-bn_mean[o], inv, bn_bias[o]));
        out = fmaf(w2[o], fmaxf(h, 0.f), out);
    }
    S[idx] = out;
}

// ---------------------------------------------------------------------------
// Kernel 2: per-pixel 3x3 reflect patches -> 8x8 covariance -> diagonal-loaded
// SPD solve (Cholesky) -> normalized weights w[pix][k]. One thread per pixel.
// softmax(a0)/sigma^2 computed inline (uniform scalar loads, ~40 VALU; this
// kernel is latency-bound at 512 waves anyway).
// ---------------------------------------------------------------------------
__global__ void capon_kernel(const float* __restrict__ S,
                             const float* __restrict__ a0_raw,    // [8]
                             const float* __restrict__ sigma_raw, // [8]
                             float* __restrict__ wOut) {          // [B*HW][8]
    int idx = blockIdx.x * blockDim.x + threadIdx.x;  // 0 .. B*HW-1
    int b  = idx >> 14;
    int hw = idx & (HW_ - 1);
    int h  = hw >> 7;
    int w  = hw & (W_ - 1);

    // inline softmax / sigma^2
    float a0[K_], sig2[K_];
    {
        float m = -1e30f;
#pragma unroll
        for (int i = 0; i < K_; ++i) m = fmaxf(m, a0_raw[i]);
        float sum = 0.f;
#pragma unroll
        for (int i = 0; i < K_; ++i) { a0[i] = __expf(a0_raw[i] - m); sum += a0[i]; }
        float invs = 1.f / sum;
#pragma unroll
        for (int i = 0; i < K_; ++i) a0[i] *= invs;
#pragma unroll
        for (int i = 0; i < K_; ++i) {
            float sg = SIGMA_MAX / (1.f + __expf(-sigma_raw[i]));
            sig2[i] = sg * sg;
        }
    }

    // reflect padding (np.pad 'reflect': -1 -> 1, H -> H-2)
    int hm = (h == 0)      ? 1       : h - 1;
    int hp = (h == H_ - 1) ? H_ - 2  : h + 1;
    int wm = (w == 0)      ? 1       : w - 1;
    int wp = (w == W_ - 1) ? W_ - 2  : w + 1;
    int rows[3] = {hm * W_, h * W_, hp * W_};
    int cols[3] = {wm, w, wp};

    float pc[K_][9];
#pragma unroll
    for (int k = 0; k < K_; ++k) {
        const float* sp = S + (((size_t)b * K_ + k) << 14);
        float p[9];
        float m = 0.f;
#pragma unroll
        for (int i = 0; i < 3; ++i)
#pragma unroll
            for (int j = 0; j < 3; ++j) {
                float v = sp[rows[i] + cols[j]];
                p[i * 3 + j] = v;
                m += v;
            }
        m *= (1.f / 9.f);
#pragma unroll
        for (int n = 0; n < 9; ++n) pc[k][n] = p[n] - m;
    }

    // A = 0.9*R + (0.1*tr(R)/K + delta)*I + diag(sig2); R[i][j] = pc_i·pc_j / 9
    float A[K_][K_];
    float tr = 0.f;
#pragma unroll
    for (int i = 0; i < K_; ++i) {
        float s = 0.f;
#pragma unroll
        for (int n = 0; n < 9; ++n) s = fmaf(pc[i][n], pc[i][n], s);
        s *= (1.f / 9.f);
        tr += s;
        A[i][i] = s;
    }
#pragma unroll
    for (int i = 0; i < K_; ++i)
#pragma unroll
        for (int j = 0; j < i; ++j) {
            float s = 0.f;
#pragma unroll
            for (int n = 0; n < 9; ++n) s = fmaf(pc[i][n], pc[j][n], s);
            A[i][j] = (1.f - COV_SHRINK) * s * (1.f / 9.f);
        }
    float dl = COV_SHRINK * tr * (1.f / (float)K_) + COV_DELTA;
#pragma unroll
    for (int i = 0; i < K_; ++i)
        A[i][i] = (1.f - COV_SHRINK) * A[i][i] + dl + sig2[i];

    // Cholesky A = L L^T (L overwrites lower triangle of A)
#pragma unroll
    for (int j = 0; j < K_; ++j) {
        float d = A[j][j];
#pragma unroll
        for (int t = 0; t < j; ++t) d = fmaf(-A[j][t], A[j][t], d);
        d = sqrtf(d);
        A[j][j] = d;
        float inv = 1.f / d;
#pragma unroll
        for (int i = j + 1; i < K_; ++i) {
            float s = A[i][j];
#pragma unroll
            for (int t = 0; t < j; ++t) s = fmaf(-A[i][t], A[j][t], s);
            A[i][j] = s * inv;
        }
    }
    // forward solve L z = a0
    float z[K_];
#pragma unroll
    for (int i = 0; i < K_; ++i) {
        float s = a0[i];
#pragma unroll
        for (int t = 0; t < i; ++t) s = fmaf(-A[i][t], z[t], s);
        z[i] = s / A[i][i];
    }
    // back solve L^T x = z
    float x[K_];
#pragma unroll
    for (int i = K_ - 1; i >= 0; --i) {
        float s = z[i];
#pragma unroll
        for (int t = i + 1; t < K_; ++t) s = fmaf(-A[t][i], x[t], s);
        x[i] = s / A[i][i];
    }
    float denom = 0.f;
#pragma unroll
    for (int k = 0; k < K_; ++k) denom = fmaf(x[k], a0[k], denom);
    float invd = 1.f / denom;

    float4 o0 = make_float4(x[0] * invd, x[1] * invd, x[2] * invd, x[3] * invd);
    float4 o1 = make_float4(x[4] * invd, x[5] * invd, x[6] * invd, x[7] * invd);
    float4* dst = (float4*)(wOut + (size_t)idx * K_);
    dst[0] = o0;
    dst[1] = o1;
}

// ---------------------------------------------------------------------------
// Kernel 3: weighted fusion. One thread per output element (b,c,h,w).
// Y[b,c,h,w] = sum_k w[b,h,w,k] * X[b,k,c,h,w]
// X should be L3-resident from stage1's read. Nontemporal store for out.
// ---------------------------------------------------------------------------
__global__ void __launch_bounds__(256)
fuse_kernel(const float* __restrict__ X,
            const float* __restrict__ wW,   // [B*HW][8]
            float* __restrict__ out) {
    int idx = blockIdx.x * blockDim.x + threadIdx.x;  // 0 .. B*C*HW-1
    int hw = idx & (HW_ - 1);
    int bc = idx >> 14;
    int b = bc >> 6;
    int c = bc & (C_ - 1);
    size_t pix = ((size_t)b << 14) + hw;

    const float4* wv4 = (const float4*)(wW + pix * K_);
    float4 wa = wv4[0];
    float4 wb = wv4[1];

    const float* xp = X + (((size_t)b * K_) * C_ + c) * HW_ + hw;
    const size_t kstride = (size_t)C_ * HW_;

    float acc;
    acc = wa.x * xp[0];
    acc = fmaf(wa.y, xp[kstride * 1], acc);
    acc = fmaf(wa.z, xp[kstride * 2], acc);
    acc = fmaf(wa.w, xp[kstride * 3], acc);
    acc = fmaf(wb.x, xp[kstride * 4], acc);
    acc = fmaf(wb.y, xp[kstride * 5], acc);
    acc = fmaf(wb.z, xp[kstride * 6], acc);
    acc = fmaf(wb.w, xp[kstride * 7], acc);
    __builtin_nontemporal_store(acc, &out[idx]);
}

// ---------------------------------------------------------------------------
extern "C" void kernel_launch(void* const* d_in, const int* in_sizes, int n_in,
                              void* d_out, int out_size, void* d_ws, size_t ws_size,
                              hipStream_t stream) {
    const float* X         = (const float*)d_in[0];
    const float* w1        = (const float*)d_in[1];
    const float* bn_scale  = (const float*)d_in[2];
    const float* bn_bias   = (const float*)d_in[3];
    const float* bn_mean   = (const float*)d_in[4];
    const float* bn_var    = (const float*)d_in[5];
    const float* w2        = (const float*)d_in[6];
    const float* a0_raw    = (const float*)d_in[7];
    const float* sigma_raw = (const float*)d_in[8];
    float* out = (float*)d_out;
    float* ws  = (float*)d_ws;

    float* S  = ws;                         // B*K*HW = 262144 floats
    float* wW = ws + (B_ * K_ * HW_);       // B*HW*K = 262144 floats

    int n1 = B_ * K_ * HW_;                 // 262144
    stage1_kernel<<<n1 / 256, 256, 0, stream>>>(X, w1, bn_scale, bn_bias,
                                                bn_mean, bn_var, w2, S);

    int n2 = B_ * HW_;                      // 32768
    capon_kernel<<<n2 / 256, 256, 0, stream>>>(S, a0_raw, sigma_raw, wW);

    int n3 = B_ * C_ * HW_;                 // 2097152
    fuse_kernel<<<n3 / 256, 256, 0, stream>>>(X, wW, out);
}

// Round 3
// 156.421 us; speedup vs baseline: 1.0187x; 1.0187x over previous
//
#include <hip/hip_runtime.h>
#include <hip/hip_bf16.h>
#include <math.h>

// Problem constants
#define B_    2
#define K_    8
#define C_    64
#define CH_   32      // C/2
#define H_    128
#define W_    128
#define HW_   16384   // H*W
#define BN_EPS 1e-5f
#define SIGMA_MAX 0.3f
#define COV_SHRINK 0.1f
#define COV_DELTA 1e-3f

// ---------------------------------------------------------------------------
// Kernel 0: fold BN into w1 and transpose to wf[c][o] (contiguous in o so
// stage1's inner-loop weights are s_load_dwordx16 wave-uniform loads).
//   par[0..2047]  wf[c][o] = w1[o][c] * bn_scale[o]/sqrt(var[o]+eps)
//   par[2048+o]   beff[o]  = bn_bias[o] - bn_mean[o]*inv_std[o]
//   par[2080+o]   w2[o]
// ---------------------------------------------------------------------------
__global__ void prep_kernel(const float* __restrict__ w1,
                            const float* __restrict__ bn_scale,
                            const float* __restrict__ bn_bias,
                            const float* __restrict__ bn_mean,
                            const float* __restrict__ bn_var,
                            const float* __restrict__ w2,
                            float* __restrict__ par) {
    int t = threadIdx.x;
    for (int i = t; i < CH_ * C_; i += blockDim.x) {
        int c = i >> 5;         // 0..63
        int o = i & 31;         // 0..31
        float inv = bn_scale[o] * rsqrtf(bn_var[o] + BN_EPS);
        par[c * CH_ + o] = w1[o * C_ + c] * inv;
    }
    if (t < CH_) {
        float inv = bn_scale[t] * rsqrtf(bn_var[t] + BN_EPS);
        par[2048 + t] = bn_bias[t] - bn_mean[t] * inv;
        par[2080 + t] = w2[t];
    }
}

// ---------------------------------------------------------------------------
// Kernel 1: sensor maps. TWO pixels per thread (float2 coalesced X loads).
// c-outer: per channel, one float2 load + 64 v_fmac with SGPR weight operand.
// acc register budget: 64 acc + ~10 misc = ~75 VGPR; cap at 128 via
// __launch_bounds__(256,4) so nothing spills (round-2 lesson: VGPR=40 meant
// the compiler spilled x[64] and the kernel went 48us latency-bound).
// ---------------------------------------------------------------------------
__global__ void __launch_bounds__(256, 4)
stage1_kernel(const float* __restrict__ X,
              const float* __restrict__ wf,    // [64][32] contiguous in o
              const float* __restrict__ beff,  // [32]
              const float* __restrict__ w2c,   // [32]
              float* __restrict__ S) {
    int t = blockIdx.x * blockDim.x + threadIdx.x;   // 0 .. B*K*HW/2-1
    int hw2 = t & (HW_ / 2 - 1);                     // float2 index in image
    int bk  = t >> 13;
    const float2* xp = (const float2*)(X + (size_t)bk * (C_ * HW_)) + hw2;

    float acc0[CH_], acc1[CH_];
#pragma unroll
    for (int o = 0; o < CH_; ++o) { acc0[o] = beff[o]; acc1[o] = beff[o]; }

#pragma unroll 8
    for (int c = 0; c < C_; ++c) {
        float2 xv = xp[(size_t)c * (HW_ / 2)];
        const float* wrow = wf + c * CH_;            // wave-uniform scalar row
#pragma unroll
        for (int o = 0; o < CH_; ++o) {
            acc0[o] = fmaf(wrow[o], xv.x, acc0[o]);
            acc1[o] = fmaf(wrow[o], xv.y, acc1[o]);
        }
    }
    float s0 = 0.f, s1 = 0.f;
#pragma unroll
    for (int o = 0; o < CH_; ++o) {
        s0 = fmaf(w2c[o], fmaxf(acc0[o], 0.f), s0);
        s1 = fmaf(w2c[o], fmaxf(acc1[o], 0.f), s1);
    }
    ((float2*)S)[t] = make_float2(s0, s1);
}

// ---------------------------------------------------------------------------
// Kernel 2: per-pixel 3x3 reflect patches -> 8x8 covariance -> diagonal-loaded
// SPD solve (Cholesky) -> normalized weights w[pix][8]. One thread per pixel.
// Latency-bound (only 512 waves): block=64 so 512 blocks cover all 256 CUs.
// ---------------------------------------------------------------------------
__global__ void capon_kernel(const float* __restrict__ S,
                             const float* __restrict__ a0_raw,    // [8]
                             const float* __restrict__ sigma_raw, // [8]
                             float* __restrict__ wOut) {          // [B*HW][8]
    int idx = blockIdx.x * blockDim.x + threadIdx.x;  // 0 .. B*HW-1
    int b  = idx >> 14;
    int hw = idx & (HW_ - 1);
    int h  = hw >> 7;
    int w  = hw & (W_ - 1);

    // inline softmax / sigma^2 (uniform scalar math)
    float a0[K_], sig2[K_];
    {
        float m = -1e30f;
#pragma unroll
        for (int i = 0; i < K_; ++i) m = fmaxf(m, a0_raw[i]);
        float sum = 0.f;
#pragma unroll
        for (int i = 0; i < K_; ++i) { a0[i] = __expf(a0_raw[i] - m); sum += a0[i]; }
        float invs = 1.f / sum;
#pragma unroll
        for (int i = 0; i < K_; ++i) a0[i] *= invs;
#pragma unroll
        for (int i = 0; i < K_; ++i) {
            float sg = SIGMA_MAX / (1.f + __expf(-sigma_raw[i]));
            sig2[i] = sg * sg;
        }
    }

    // reflect padding (np.pad 'reflect': -1 -> 1, H -> H-2)
    int hm = (h == 0)      ? 1       : h - 1;
    int hp = (h == H_ - 1) ? H_ - 2  : h + 1;
    int wm = (w == 0)      ? 1       : w - 1;
    int wp = (w == W_ - 1) ? W_ - 2  : w + 1;
    int rows[3] = {hm * W_, h * W_, hp * W_};
    int cols[3] = {wm, w, wp};

    float pc[K_][9];
#pragma unroll
    for (int k = 0; k < K_; ++k) {
        const float* sp = S + (((size_t)b * K_ + k) << 14);
        float p[9];
        float m = 0.f;
#pragma unroll
        for (int i = 0; i < 3; ++i)
#pragma unroll
            for (int j = 0; j < 3; ++j) {
                float v = sp[rows[i] + cols[j]];
                p[i * 3 + j] = v;
                m += v;
            }
        m *= (1.f / 9.f);
#pragma unroll
        for (int n = 0; n < 9; ++n) pc[k][n] = p[n] - m;
    }

    // A = 0.9*R + (0.1*tr(R)/K + delta)*I + diag(sig2); R[i][j] = pc_i·pc_j / 9
    float A[K_][K_];
    float tr = 0.f;
#pragma unroll
    for (int i = 0; i < K_; ++i) {
        float s = 0.f;
#pragma unroll
        for (int n = 0; n < 9; ++n) s = fmaf(pc[i][n], pc[i][n], s);
        s *= (1.f / 9.f);
        tr += s;
        A[i][i] = s;
    }
#pragma unroll
    for (int i = 0; i < K_; ++i)
#pragma unroll
        for (int j = 0; j < i; ++j) {
            float s = 0.f;
#pragma unroll
            for (int n = 0; n < 9; ++n) s = fmaf(pc[i][n], pc[j][n], s);
            A[i][j] = (1.f - COV_SHRINK) * s * (1.f / 9.f);
        }
    float dl = COV_SHRINK * tr * (1.f / (float)K_) + COV_DELTA;
#pragma unroll
    for (int i = 0; i < K_; ++i)
        A[i][i] = (1.f - COV_SHRINK) * A[i][i] + dl + sig2[i];

    // Cholesky A = L L^T
#pragma unroll
    for (int j = 0; j < K_; ++j) {
        float d = A[j][j];
#pragma unroll
        for (int t = 0; t < j; ++t) d = fmaf(-A[j][t], A[j][t], d);
        d = sqrtf(d);
        A[j][j] = d;
        float inv = 1.f / d;
#pragma unroll
        for (int i = j + 1; i < K_; ++i) {
            float s = A[i][j];
#pragma unroll
            for (int t = 0; t < j; ++t) s = fmaf(-A[i][t], A[j][t], s);
            A[i][j] = s * inv;
        }
    }
    // forward solve L z = a0
    float z[K_];
#pragma unroll
    for (int i = 0; i < K_; ++i) {
        float s = a0[i];
#pragma unroll
        for (int t = 0; t < i; ++t) s = fmaf(-A[i][t], z[t], s);
        z[i] = s / A[i][i];
    }
    // back solve L^T x = z
    float x[K_];
#pragma unroll
    for (int i = K_ - 1; i >= 0; --i) {
        float s = z[i];
#pragma unroll
        for (int t = i + 1; t < K_; ++t) s = fmaf(-A[t][i], x[t], s);
        x[i] = s / A[i][i];
    }
    float denom = 0.f;
#pragma unroll
    for (int k = 0; k < K_; ++k) denom = fmaf(x[k], a0[k], denom);
    float invd = 1.f / denom;

    float4 o0 = make_float4(x[0] * invd, x[1] * invd, x[2] * invd, x[3] * invd);
    float4 o1 = make_float4(x[4] * invd, x[5] * invd, x[6] * invd, x[7] * invd);
    float4* dst = (float4*)(wOut + (size_t)idx * K_);
    dst[0] = o0;
    dst[1] = o1;
}

// ---------------------------------------------------------------------------
// Kernel 3: weighted fusion. One thread per output element (b,c,h,w).
// Y[b,c,h,w] = sum_k w[b,h,w,k] * X[b,k,c,h,w]; X is L3-resident by now.
// ---------------------------------------------------------------------------
__global__ void __launch_bounds__(256)
fuse_kernel(const float* __restrict__ X,
            const float* __restrict__ wW,   // [B*HW][8]
            float* __restrict__ out) {
    int idx = blockIdx.x * blockDim.x + threadIdx.x;  // 0 .. B*C*HW-1
    int hw = idx & (HW_ - 1);
    int bc = idx >> 14;
    int b = bc >> 6;
    int c = bc & (C_ - 1);
    size_t pix = ((size_t)b << 14) + hw;

    const float4* wv4 = (const float4*)(wW + pix * K_);
    float4 wa = wv4[0];
    float4 wb = wv4[1];

    const float* xp = X + (((size_t)b * K_) * C_ + c) * HW_ + hw;
    const size_t kstride = (size_t)C_ * HW_;

    float acc;
    acc = wa.x * xp[0];
    acc = fmaf(wa.y, xp[kstride * 1], acc);
    acc = fmaf(wa.z, xp[kstride * 2], acc);
    acc = fmaf(wa.w, xp[kstride * 3], acc);
    acc = fmaf(wb.x, xp[kstride * 4], acc);
    acc = fmaf(wb.y, xp[kstride * 5], acc);
    acc = fmaf(wb.z, xp[kstride * 6], acc);
    acc = fmaf(wb.w, xp[kstride * 7], acc);
    __builtin_nontemporal_store(acc, &out[idx]);
}

// ---------------------------------------------------------------------------
extern "C" void kernel_launch(void* const* d_in, const int* in_sizes, int n_in,
                              void* d_out, int out_size, void* d_ws, size_t ws_size,
                              hipStream_t stream) {
    const float* X         = (const float*)d_in[0];
    const float* w1        = (const float*)d_in[1];
    const float* bn_scale  = (const float*)d_in[2];
    const float* bn_bias   = (const float*)d_in[3];
    const float* bn_mean   = (const float*)d_in[4];
    const float* bn_var    = (const float*)d_in[5];
    const float* w2        = (const float*)d_in[6];
    const float* a0_raw    = (const float*)d_in[7];
    const float* sigma_raw = (const float*)d_in[8];
    float* out = (float*)d_out;
    float* ws  = (float*)d_ws;

    float* par = ws;                         // 4096 floats (params)
    float* S   = ws + 4096;                  // B*K*HW = 262144 floats
    float* wW  = ws + 4096 + (B_ * K_ * HW_);// B*HW*K = 262144 floats

    prep_kernel<<<1, 256, 0, stream>>>(w1, bn_scale, bn_bias, bn_mean, bn_var,
                                       w2, par);

    int n1 = B_ * K_ * HW_ / 2;              // 131072 threads (2 px each)
    stage1_kernel<<<n1 / 256, 256, 0, stream>>>(X, par, par + 2048, par + 2080, S);

    int n2 = B_ * HW_;                       // 32768
    capon_kernel<<<n2 / 64, 64, 0, stream>>>(S, a0_raw, sigma_raw, wW);

    int n3 = B_ * C_ * HW_;                  // 2097152
    fuse_kernel<<<n3 / 256, 256, 0, stream>>>(X, wW, out);
}

// Round 4
// 141.025 us; speedup vs baseline: 1.1299x; 1.1092x over previous
//
#include <hip/hip_runtime.h>
#include <hip/hip_bf16.h>
#include <math.h>

// Problem constants
#define B_    2
#define K_    8
#define C_    64
#define CH_   32      // C/2
#define H_    128
#define W_    128
#define HW_   16384   // H*W
#define BN_EPS 1e-5f
#define SIGMA_MAX 0.3f
#define COV_SHRINK 0.1f
#define COV_DELTA 1e-3f

// 32-way repeat macro: generates NAMED scalar accumulators so the compiler
// can never turn them into scratch (rounds 1-3 lesson: acc[32] arrays were
// dynamically indexed when the unroller gave up -> scratch-thrash, 47us).
#define REP32(M) \
    M(0)  M(1)  M(2)  M(3)  M(4)  M(5)  M(6)  M(7)  \
    M(8)  M(9)  M(10) M(11) M(12) M(13) M(14) M(15) \
    M(16) M(17) M(18) M(19) M(20) M(21) M(22) M(23) \
    M(24) M(25) M(26) M(27) M(28) M(29) M(30) M(31)

// ---------------------------------------------------------------------------
// Kernel 0: fold BN into w1 and transpose to wf[c][o] (contiguous in o so
// stage1's weights are wave-uniform s_load_dwordx16 loads).
//   par[0..2047]  wf[c][o] = w1[o][c] * bn_scale[o]/sqrt(var[o]+eps)
//   par[2048+o]   beff[o]  = bn_bias[o] - bn_mean[o]*inv_std[o]
//   par[2080+o]   w2[o]
// ---------------------------------------------------------------------------
__global__ void prep_kernel(const float* __restrict__ w1,
                            const float* __restrict__ bn_scale,
                            const float* __restrict__ bn_bias,
                            const float* __restrict__ bn_mean,
                            const float* __restrict__ bn_var,
                            const float* __restrict__ w2,
                            float* __restrict__ par) {
    int t = threadIdx.x;
    for (int i = t; i < CH_ * C_; i += blockDim.x) {
        int c = i >> 5;         // 0..63
        int o = i & 31;         // 0..31
        float inv = bn_scale[o] * rsqrtf(bn_var[o] + BN_EPS);
        par[c * CH_ + o] = w1[o * C_ + c] * inv;
    }
    if (t < CH_) {
        float inv = bn_scale[t] * rsqrtf(bn_var[t] + BN_EPS);
        par[2048 + t] = bn_bias[t] - bn_mean[t] * inv;
        par[2080 + t] = w2[t];
    }
}

// ---------------------------------------------------------------------------
// Kernel 1: sensor maps. ONE pixel per thread, 32 NAMED accumulators.
// Per c: one coalesced dword X load + 32 v_fmac with SGPR weight operands.
// 262144 threads -> 1024 blocks -> 4 blocks/CU, 16 waves/CU.
// VALU floor ~14us, HBM floor ~10us.
// ---------------------------------------------------------------------------
__global__ void __launch_bounds__(256)
stage1_kernel(const float* __restrict__ X,
              const float* __restrict__ wf,    // [64][32] contiguous in o
              const float* __restrict__ beff,  // [32]
              const float* __restrict__ w2c,   // [32]
              float* __restrict__ S) {
    int idx = blockIdx.x * blockDim.x + threadIdx.x;   // 0 .. B*K*HW-1
    int hw = idx & (HW_ - 1);
    int bk = idx >> 14;
    const float* xp = X + (size_t)bk * (C_ * HW_) + hw;

#define DECL_ACC(o) float a##o = beff[o];
    REP32(DECL_ACC)
#undef DECL_ACC

#pragma unroll 2
    for (int c = 0; c < C_; ++c) {
        float xv = xp[(size_t)c * HW_];
        const float* wr = wf + c * CH_;        // wave-uniform -> s_load
#define FMA_ONE(o) a##o = fmaf(wr[o], xv, a##o);
        REP32(FMA_ONE)
#undef FMA_ONE
    }

    float s = 0.f;
#define REDUCE_ONE(o) s = fmaf(w2c[o], fmaxf(a##o, 0.f), s);
    REP32(REDUCE_ONE)
#undef REDUCE_ONE
    S[idx] = s;
}

// ---------------------------------------------------------------------------
// Kernel 2: per-pixel 3x3 reflect patches -> 8x8 covariance -> diagonal-loaded
// SPD solve (Cholesky) -> normalized weights w[pix][8]. One thread per pixel.
// Latency-bound (512 waves): block=64 so 512 blocks cover all 256 CUs.
// ---------------------------------------------------------------------------
__global__ void capon_kernel(const float* __restrict__ S,
                             const float* __restrict__ a0_raw,    // [8]
                             const float* __restrict__ sigma_raw, // [8]
                             float* __restrict__ wOut) {          // [B*HW][8]
    int idx = blockIdx.x * blockDim.x + threadIdx.x;  // 0 .. B*HW-1
    int b  = idx >> 14;
    int hw = idx & (HW_ - 1);
    int h  = hw >> 7;
    int w  = hw & (W_ - 1);

    // inline softmax / sigma^2 (uniform scalar math)
    float a0[K_], sig2[K_];
    {
        float m = -1e30f;
#pragma unroll
        for (int i = 0; i < K_; ++i) m = fmaxf(m, a0_raw[i]);
        float sum = 0.f;
#pragma unroll
        for (int i = 0; i < K_; ++i) { a0[i] = __expf(a0_raw[i] - m); sum += a0[i]; }
        float invs = 1.f / sum;
#pragma unroll
        for (int i = 0; i < K_; ++i) a0[i] *= invs;
#pragma unroll
        for (int i = 0; i < K_; ++i) {
            float sg = SIGMA_MAX / (1.f + __expf(-sigma_raw[i]));
            sig2[i] = sg * sg;
        }
    }

    // reflect padding (np.pad 'reflect': -1 -> 1, H -> H-2)
    int hm = (h == 0)      ? 1       : h - 1;
    int hp = (h == H_ - 1) ? H_ - 2  : h + 1;
    int wm = (w == 0)      ? 1       : w - 1;
    int wp = (w == W_ - 1) ? W_ - 2  : w + 1;
    int rows[3] = {hm * W_, h * W_, hp * W_};
    int cols[3] = {wm, w, wp};

    float pc[K_][9];
#pragma unroll
    for (int k = 0; k < K_; ++k) {
        const float* sp = S + (((size_t)b * K_ + k) << 14);
        float p[9];
        float m = 0.f;
#pragma unroll
        for (int i = 0; i < 3; ++i)
#pragma unroll
            for (int j = 0; j < 3; ++j) {
                float v = sp[rows[i] + cols[j]];
                p[i * 3 + j] = v;
                m += v;
            }
        m *= (1.f / 9.f);
#pragma unroll
        for (int n = 0; n < 9; ++n) pc[k][n] = p[n] - m;
    }

    // A = 0.9*R + (0.1*tr(R)/K + delta)*I + diag(sig2); R[i][j] = pc_i·pc_j / 9
    float A[K_][K_];
    float tr = 0.f;
#pragma unroll
    for (int i = 0; i < K_; ++i) {
        float s = 0.f;
#pragma unroll
        for (int n = 0; n < 9; ++n) s = fmaf(pc[i][n], pc[i][n], s);
        s *= (1.f / 9.f);
        tr += s;
        A[i][i] = s;
    }
#pragma unroll
    for (int i = 0; i < K_; ++i)
#pragma unroll
        for (int j = 0; j < i; ++j) {
            float s = 0.f;
#pragma unroll
            for (int n = 0; n < 9; ++n) s = fmaf(pc[i][n], pc[j][n], s);
            A[i][j] = (1.f - COV_SHRINK) * s * (1.f / 9.f);
        }
    float dl = COV_SHRINK * tr * (1.f / (float)K_) + COV_DELTA;
#pragma unroll
    for (int i = 0; i < K_; ++i)
        A[i][i] = (1.f - COV_SHRINK) * A[i][i] + dl + sig2[i];

    // Cholesky A = L L^T
#pragma unroll
    for (int j = 0; j < K_; ++j) {
        float d = A[j][j];
#pragma unroll
        for (int t = 0; t < j; ++t) d = fmaf(-A[j][t], A[j][t], d);
        d = sqrtf(d);
        A[j][j] = d;
        float inv = 1.f / d;
#pragma unroll
        for (int i = j + 1; i < K_; ++i) {
            float s = A[i][j];
#pragma unroll
            for (int t = 0; t < j; ++t) s = fmaf(-A[i][t], A[j][t], s);
            A[i][j] = s * inv;
        }
    }
    // forward solve L z = a0
    float z[K_];
#pragma unroll
    for (int i = 0; i < K_; ++i) {
        float s = a0[i];
#pragma unroll
        for (int t = 0; t < i; ++t) s = fmaf(-A[i][t], z[t], s);
        z[i] = s / A[i][i];
    }
    // back solve L^T x = z
    float x[K_];
#pragma unroll
    for (int i = K_ - 1; i >= 0; --i) {
        float s = z[i];
#pragma unroll
        for (int t = i + 1; t < K_; ++t) s = fmaf(-A[t][i], x[t], s);
        x[i] = s / A[i][i];
    }
    float denom = 0.f;
#pragma unroll
    for (int k = 0; k < K_; ++k) denom = fmaf(x[k], a0[k], denom);
    float invd = 1.f / denom;

    float4 o0 = make_float4(x[0] * invd, x[1] * invd, x[2] * invd, x[3] * invd);
    float4 o1 = make_float4(x[4] * invd, x[5] * invd, x[6] * invd, x[7] * invd);
    float4* dst = (float4*)(wOut + (size_t)idx * K_);
    dst[0] = o0;
    dst[1] = o1;
}

// ---------------------------------------------------------------------------
// Kernel 3: weighted fusion. One thread per output element (b,c,h,w).
// Y[b,c,h,w] = sum_k w[b,h,w,k] * X[b,k,c,h,w]; X is L3-resident by now.
// ---------------------------------------------------------------------------
__global__ void __launch_bounds__(256)
fuse_kernel(const float* __restrict__ X,
            const float* __restrict__ wW,   // [B*HW][8]
            float* __restrict__ out) {
    int idx = blockIdx.x * blockDim.x + threadIdx.x;  // 0 .. B*C*HW-1
    int hw = idx & (HW_ - 1);
    int bc = idx >> 14;
    int b = bc >> 6;
    int c = bc & (C_ - 1);
    size_t pix = ((size_t)b << 14) + hw;

    const float4* wv4 = (const float4*)(wW + pix * K_);
    float4 wa = wv4[0];
    float4 wb = wv4[1];

    const float* xp = X + (((size_t)b * K_) * C_ + c) * HW_ + hw;
    const size_t kstride = (size_t)C_ * HW_;

    float acc;
    acc = wa.x * xp[0];
    acc = fmaf(wa.y, xp[kstride * 1], acc);
    acc = fmaf(wa.z, xp[kstride * 2], acc);
    acc = fmaf(wa.w, xp[kstride * 3], acc);
    acc = fmaf(wb.x, xp[kstride * 4], acc);
    acc = fmaf(wb.y, xp[kstride * 5], acc);
    acc = fmaf(wb.z, xp[kstride * 6], acc);
    acc = fmaf(wb.w, xp[kstride * 7], acc);
    __builtin_nontemporal_store(acc, &out[idx]);
}

// ---------------------------------------------------------------------------
extern "C" void kernel_launch(void* const* d_in, const int* in_sizes, int n_in,
                              void* d_out, int out_size, void* d_ws, size_t ws_size,
                              hipStream_t stream) {
    const float* X         = (const float*)d_in[0];
    const float* w1        = (const float*)d_in[1];
    const float* bn_scale  = (const float*)d_in[2];
    const float* bn_bias   = (const float*)d_in[3];
    const float* bn_mean   = (const float*)d_in[4];
    const float* bn_var    = (const float*)d_in[5];
    const float* w2        = (const float*)d_in[6];
    const float* a0_raw    = (const float*)d_in[7];
    const float* sigma_raw = (const float*)d_in[8];
    float* out = (float*)d_out;
    float* ws  = (float*)d_ws;

    float* par = ws;                         // 4096 floats (params)
    float* S   = ws + 4096;                  // B*K*HW = 262144 floats
    float* wW  = ws + 4096 + (B_ * K_ * HW_);// B*HW*K = 262144 floats

    prep_kernel<<<1, 256, 0, stream>>>(w1, bn_scale, bn_bias, bn_mean, bn_var,
                                       w2, par);

    int n1 = B_ * K_ * HW_;                  // 262144 threads (1 px each)
    stage1_kernel<<<n1 / 256, 256, 0, stream>>>(X, par, par + 2048, par + 2080, S);

    int n2 = B_ * HW_;                       // 32768
    capon_kernel<<<n2 / 64, 64, 0, stream>>>(S, a0_raw, sigma_raw, wW);

    int n3 = B_ * C_ * HW_;                  // 2097152
    fuse_kernel<<<n3 / 256, 256, 0, stream>>>(X, wW, out);
}